// Round 1
// baseline (127.728 us; speedup 1.0000x reference)
//
#include <hip/hip_runtime.h>
#include <math.h>

#define HIDDEN 1024
#define NF4 256          // float4 per row
#define NEXP 64
#define ROWS 32
#define TOPK 4
#define INNER 8
#define TOTAL 8
#define TB 4             // tokens per block, phase 1 (256 blocks)
#define G2 16            // pairs per block, phase 2 (2x arithmetic intensity vs G=8)
#define MAXCH 10         // 10*16 = 160 pairs/expert capacity (same as proven round 5)

__device__ __forceinline__ float dot4(float4 a, float4 b) {
    return a.x * b.x + a.y * b.y + a.z * b.z + a.w * b.w;
}

// ---------------- phase 1: router + scatter + final-weight write ----------------
// 256 threads = 16 groups(g) x 16 lanes(j). Lane owns expert rows
// {g,g+16,g+32,g+48}, dim chunk c=j+16k. Weight loads are 16-lane coalesced
// 256B runs. Top-4 is wave-parallel (wave w = token w; lane e holds logit e).
// p1 also writes the weights half of `out` directly ([w0,w0,w0,w1,w1,w2,w2,w3])
// and packs into each tok_list entry the 3-bit final-output offset for that
// (token,slot) pair: off = sum of pattern counts of selected experts with
// larger index. This removes phase 3 entirely.
__global__ __launch_bounds__(256) void p1_router(
    const float* __restrict__ x, const float* __restrict__ rw,
    int* __restrict__ count, int* __restrict__ tok_list,
    float* __restrict__ out, int bs)
{
    __shared__ float4 sx[TB * NF4];      // 16 KB
    __shared__ float  red[TB][NEXP];     // 1 KB

    const int t = threadIdx.x;
    const int g = t >> 4, j = t & 15;
    const int tok0 = blockIdx.x * TB;

    {   // stage TB x rows, coalesced 16 B/lane
        const float4* xs = (const float4*)(x + (size_t)tok0 * HIDDEN);
        #pragma unroll
        for (int i = 0; i < TB; ++i) sx[i * NF4 + t] = xs[i * NF4 + t];
    }
    __syncthreads();

    const float4* wp[4];
    #pragma unroll
    for (int m = 0; m < 4; ++m)
        wp[m] = (const float4*)(rw + (size_t)(g + 16 * m) * HIDDEN);

    float acc[4][TB];
    #pragma unroll
    for (int m = 0; m < 4; ++m)
        #pragma unroll
        for (int tk = 0; tk < TB; ++tk) acc[m][tk] = 0.f;

    #pragma unroll 2
    for (int k = 0; k < 16; ++k) {
        const int c = j + 16 * k;
        float4 wf[4];                          // small batch -> loads in flight
        #pragma unroll
        for (int m = 0; m < 4; ++m) wf[m] = wp[m][c];
        #pragma unroll
        for (int tk = 0; tk < TB; ++tk) {
            float4 xb = sx[tk * NF4 + c];      // broadcast across groups: free
            #pragma unroll
            for (int m = 0; m < 4; ++m) acc[m][tk] += dot4(wf[m], xb);
        }
    }

    #pragma unroll
    for (int m = 0; m < 4; ++m)
        #pragma unroll
        for (int tk = 0; tk < TB; ++tk) {
            float v = acc[m][tk];
            v += __shfl_xor(v, 1); v += __shfl_xor(v, 2);
            v += __shfl_xor(v, 4); v += __shfl_xor(v, 8);
            acc[m][tk] = v;
        }
    if (j == 0)
        #pragma unroll
        for (int m = 0; m < 4; ++m)
            #pragma unroll
            for (int tk = 0; tk < TB; ++tk)
                red[tk][g + 16 * m] = acc[m][tk];
    __syncthreads();

    // ---- wave-parallel top-4: wave w handles token tok0+w, lane e = logit e ----
    const int w = t >> 6, lane = t & 63;
    float v = red[w][lane];
    float vals[TOPK]; int sel[TOPK];
    #pragma unroll
    for (int k = 0; k < TOPK; ++k) {
        float bv = v; int bi = lane;
        #pragma unroll
        for (int o = 32; o; o >>= 1) {         // (value, index) max-reduce,
            float ov = __shfl_xor(bv, o);      // lowest index wins ties
            int   oi = __shfl_xor(bi, o);
            if (ov > bv || (ov == bv && oi < bi)) { bv = ov; bi = oi; }
        }
        vals[k] = bv; sel[k] = bi;
        if (lane == bi) v = -INFINITY;
    }

    if (lane == 0) {
        const int token = tok0 + w;
        const float m0 = vals[0];
        float ex[TOPK], s = 0.f;
        #pragma unroll
        for (int k = 0; k < TOPK; ++k) { ex[k] = expf(vals[k] - m0); s += ex[k]; }
        const float inv = 1.f / s;
        // weights half of the output: pattern-expanded, already descending
        float* ow = out + (size_t)bs * TOTAL + (size_t)token * TOTAL;
        const float w0 = ex[0]*inv, w1 = ex[1]*inv, w2 = ex[2]*inv, w3 = ex[3]*inv;
        ow[0] = w0; ow[1] = w0; ow[2] = w0; ow[3] = w1;
        ow[4] = w1; ow[5] = w2; ow[6] = w2; ow[7] = w3;
        // scatter with packed final-output offset
        const int pat[TOPK] = {3, 2, 2, 1};
        #pragma unroll
        for (int k = 0; k < TOPK; ++k) {
            int off = 0;
            #pragma unroll
            for (int q = 0; q < TOPK; ++q)
                off += (sel[q] > sel[k]) ? pat[q] : 0;   // experts are distinct
            int pos = atomicAdd(&count[sel[k]], 1);
            tok_list[sel[k] * 1024 + pos] = (token << 6) | (k << 3) | off;
        }
    }
}

// ---------------- phase 2: expert matmuls + inner top-k + direct id write ------
// Same 4-rows-per-lane mapping over 64 rows (32 gate + 32 up), G2=16 tokens:
// 256 KB of expert weights now amortized over 16 tokens (was 8) -> weight
// traffic ~75 MB (was 133 MB) and 2x FMA per in-flight load batch.
__global__ __launch_bounds__(256) void p2_experts(
    const float* __restrict__ x,
    const float* __restrict__ wg, const float* __restrict__ wu,
    const int* __restrict__ count, const int* __restrict__ tok_list,
    float* __restrict__ out)
{
    __shared__ float4 sx[G2 * NF4];          // 64 KB
    __shared__ float  sred[G2][NEXP];        // 4 KB  [token][row 0..63]
    __shared__ float  sscore[G2][ROWS];      // 2 KB
    __shared__ int    s_entry[G2];

    const int e = blockIdx.x, c0 = blockIdx.y;
    const int n = count[e];
    const int i0 = c0 * G2;
    if (i0 >= n) return;
    const int T = (n - i0 < G2) ? (n - i0) : G2;

    const int t = threadIdx.x;
    const int g = t >> 4, j = t & 15;

    if (t < G2)
        s_entry[t] = tok_list[e * 1024 + i0 + ((t < T) ? t : 0)];  // clamp -> dup work
    __syncthreads();

    {   // stage G2 token rows, coalesced
        #pragma unroll
        for (int i = 0; i < G2; ++i)
            sx[i * NF4 + t] =
                ((const float4*)(x + (size_t)(s_entry[i] >> 6) * HIDDEN))[t];
    }
    __syncthreads();

    const float4* wp[4];
    #pragma unroll
    for (int m = 0; m < 4; ++m) {
        const int R = g + 16 * m;            // 0..31 gate rows, 32..63 up rows
        wp[m] = (const float4*)((R < ROWS)
            ? wg + ((size_t)e * ROWS + R) * HIDDEN
            : wu + ((size_t)e * ROWS + (R - ROWS)) * HIDDEN);
    }

    float acc[4][G2];
    #pragma unroll
    for (int m = 0; m < 4; ++m)
        #pragma unroll
        for (int tk = 0; tk < G2; ++tk) acc[m][tk] = 0.f;

    #pragma unroll 2
    for (int k = 0; k < 16; ++k) {
        const int c = j + 16 * k;
        float4 wf[4];
        #pragma unroll
        for (int m = 0; m < 4; ++m) wf[m] = wp[m][c];
        #pragma unroll
        for (int tk = 0; tk < G2; ++tk) {
            float4 xb = sx[tk * NF4 + c];
            #pragma unroll
            for (int m = 0; m < 4; ++m) acc[m][tk] += dot4(wf[m], xb);
        }
    }

    #pragma unroll
    for (int m = 0; m < 4; ++m)
        #pragma unroll
        for (int tk = 0; tk < G2; ++tk) {
            float v = acc[m][tk];
            v += __shfl_xor(v, 1); v += __shfl_xor(v, 2);
            v += __shfl_xor(v, 4); v += __shfl_xor(v, 8);
            acc[m][tk] = v;
        }
    if (j == 0)
        #pragma unroll
        for (int m = 0; m < 4; ++m)
            #pragma unroll
            for (int tk = 0; tk < G2; ++tk)
                sred[tk][g + 16 * m] = acc[m][tk];
    __syncthreads();

    {   // silu-gate-abs: 512 items, 256 threads x 2
        #pragma unroll
        for (int it = 0; it < (G2 * ROWS) / 256; ++it) {
            const int idx = it * 256 + t;
            const int tok = idx >> 5, rr = idx & 31;
            const float gg = sred[tok][rr], uu = sred[tok][rr + 32];
            sscore[tok][rr] = fabsf(uu * (gg / (1.f + expf(-gg))));
        }
    }
    __syncthreads();

    if (t < T) {
        const int entry = s_entry[t];
        const int token = entry >> 6, slot = (entry >> 3) & 3, off = entry & 7;
        float inner[INNER];
        #pragma unroll
        for (int i = 0; i < INNER; ++i)
            inner[i] = 0.25f * (sscore[t][4*i] + sscore[t][4*i+1]
                              + sscore[t][4*i+2] + sscore[t][4*i+3]);
        const int kk = (slot == 0) ? 3 : ((slot == 3) ? 1 : 2);
        int picked[3];
        for (int k = 0; k < kk; ++k) {
            float best = -INFINITY; int bi = 0;
            #pragma unroll
            for (int i = 0; i < INNER; ++i)
                if (inner[i] > best) { best = inner[i]; bi = i; }  // ties -> lowest idx
            inner[bi] = -INFINITY;
            picked[k] = bi;
        }
        for (int a = 1; a < kk; ++a) {       // sort inner ids descending (kk<=3)
            int vv = picked[a]; int b = a - 1;
            while (b >= 0 && picked[b] < vv) { picked[b+1] = picked[b]; --b; }
            picked[b+1] = vv;
        }
        // direct final-position write: experts descend across pairs (off from p1),
        // inner ids descend within the pair -> exactly reference's top-8 order
        float* oid = out + (size_t)token * TOTAL + off;
        for (int k = 0; k < kk; ++k) oid[k] = (float)(e * INNER + picked[k]);
    }
}

extern "C" void kernel_launch(void* const* d_in, const int* in_sizes, int n_in,
                              void* d_out, int out_size, void* d_ws, size_t ws_size,
                              hipStream_t stream) {
    const float* x  = (const float*)d_in[0];
    const float* rw = (const float*)d_in[1];
    const float* wg = (const float*)d_in[2];
    const float* wu = (const float*)d_in[3];
    float* out = (float*)d_out;
    const int bs = in_sizes[0] / HIDDEN;   // 1024

    // workspace: count[64] | tok_list[64*1024]
    int* count    = (int*)d_ws;
    int* tok_list = count + 64;

    hipMemsetAsync(count, 0, 64 * sizeof(int), stream);
    hipLaunchKernelGGL(p1_router, dim3(bs / TB), dim3(256), 0, stream,
                       x, rw, count, tok_list, out, bs);
    hipLaunchKernelGGL(p2_experts, dim3(NEXP, MAXCH), dim3(256), 0, stream,
                       x, wg, wu, count, tok_list, out);
}

// Round 3
// 123.932 us; speedup vs baseline: 1.0306x; 1.0306x over previous
//
#include <hip/hip_runtime.h>
#include <math.h>

#define HIDDEN 1024
#define NF4 256          // float4 per row
#define NEXP 64
#define ROWS 32
#define TOPK 4
#define INNER 8
#define TOTAL 8
#define TB 4             // tokens per block, phase 1 (256 blocks)
#define G 8              // pairs per block, phase 2 (35 KB LDS -> 4 blocks/CU)
#define MAXCH 20         // 20*8 = 160 pairs/expert capacity (proven sufficient)

__device__ __forceinline__ float dot4(float4 a, float4 b) {
    return a.x * b.x + a.y * b.y + a.z * b.z + a.w * b.w;
}

// ---------------- phase 1: router + scatter + final-weight write ----------------
// 256 threads = 16 groups(g) x 16 lanes(j). Lane owns expert rows
// {g,g+16,g+32,g+48}, dim chunk c=j+16k. Weight loads are 16-lane coalesced
// 256B runs. Top-4 is wave-parallel (wave w = token w; lane e holds logit e).
// Writes the weights half of `out` directly ([w0,w0,w0,w1,w1,w2,w2,w3]) and
// packs into each tok_list entry the 3-bit final-output offset for that
// (token,slot) pair: off = sum of pattern counts of selected experts with
// larger index. (Both proven in round 1, absmax 0.)
__global__ __launch_bounds__(256) void p1_router(
    const float* __restrict__ x, const float* __restrict__ rw,
    int* __restrict__ count, int* __restrict__ tok_list,
    float* __restrict__ out, int bs)
{
    __shared__ float4 sx[TB * NF4];      // 16 KB
    __shared__ float  red[TB][NEXP];     // 1 KB

    const int t = threadIdx.x;
    const int g = t >> 4, j = t & 15;
    const int tok0 = blockIdx.x * TB;

    {   // stage TB x rows, coalesced 16 B/lane
        const float4* xs = (const float4*)(x + (size_t)tok0 * HIDDEN);
        #pragma unroll
        for (int i = 0; i < TB; ++i) sx[i * NF4 + t] = xs[i * NF4 + t];
    }
    __syncthreads();

    const float4* wp[4];
    #pragma unroll
    for (int m = 0; m < 4; ++m)
        wp[m] = (const float4*)(rw + (size_t)(g + 16 * m) * HIDDEN);

    float acc[4][TB];
    #pragma unroll
    for (int m = 0; m < 4; ++m)
        #pragma unroll
        for (int tk = 0; tk < TB; ++tk) acc[m][tk] = 0.f;

    #pragma unroll 2
    for (int k = 0; k < 16; ++k) {
        const int c = j + 16 * k;
        float4 wf[4];                          // small batch -> loads in flight
        #pragma unroll
        for (int m = 0; m < 4; ++m) wf[m] = wp[m][c];
        #pragma unroll
        for (int tk = 0; tk < TB; ++tk) {
            float4 xb = sx[tk * NF4 + c];      // broadcast across groups: free
            #pragma unroll
            for (int m = 0; m < 4; ++m) acc[m][tk] += dot4(wf[m], xb);
        }
    }

    #pragma unroll
    for (int m = 0; m < 4; ++m)
        #pragma unroll
        for (int tk = 0; tk < TB; ++tk) {
            float v = acc[m][tk];
            v += __shfl_xor(v, 1); v += __shfl_xor(v, 2);
            v += __shfl_xor(v, 4); v += __shfl_xor(v, 8);
            acc[m][tk] = v;
        }
    if (j == 0)
        #pragma unroll
        for (int m = 0; m < 4; ++m)
            #pragma unroll
            for (int tk = 0; tk < TB; ++tk)
                red[tk][g + 16 * m] = acc[m][tk];
    __syncthreads();

    // ---- wave-parallel top-4: wave w = token tok0+w, lane e = logit e ----
    const int w = t >> 6, lane = t & 63;
    float v = red[w][lane];
    float vals[TOPK]; int sel[TOPK];
    #pragma unroll
    for (int k = 0; k < TOPK; ++k) {
        float bv = v; int bi = lane;
        #pragma unroll
        for (int o = 32; o; o >>= 1) {         // (value, index) max-reduce,
            float ov = __shfl_xor(bv, o);      // lowest index wins ties
            int   oi = __shfl_xor(bi, o);
            if (ov > bv || (ov == bv && oi < bi)) { bv = ov; bi = oi; }
        }
        vals[k] = bv; sel[k] = bi;
        if (lane == bi) v = -INFINITY;
    }

    if (lane == 0) {
        const int token = tok0 + w;
        const float m0 = vals[0];
        float ex[TOPK], s = 0.f;
        #pragma unroll
        for (int k = 0; k < TOPK; ++k) { ex[k] = expf(vals[k] - m0); s += ex[k]; }
        const float inv = 1.f / s;
        // weights half of the output: pattern-expanded, already descending
        float* ow = out + (size_t)bs * TOTAL + (size_t)token * TOTAL;
        const float w0 = ex[0]*inv, w1 = ex[1]*inv, w2 = ex[2]*inv, w3 = ex[3]*inv;
        ow[0] = w0; ow[1] = w0; ow[2] = w0; ow[3] = w1;
        ow[4] = w1; ow[5] = w2; ow[6] = w2; ow[7] = w3;
        // scatter with packed final-output offset
        const int pat[TOPK] = {3, 2, 2, 1};
        #pragma unroll
        for (int k = 0; k < TOPK; ++k) {
            int off = 0;
            #pragma unroll
            for (int q = 0; q < TOPK; ++q)
                off += (sel[q] > sel[k]) ? pat[q] : 0;   // experts are distinct
            int pos = atomicAdd(&count[sel[k]], 1);
            tok_list[sel[k] * 1024 + pos] = (token << 6) | (k << 3) | off;
        }
    }
}

// ---------------- phase 2: expert matmuls + inner top-k + direct id write ------
// Round-0 geometry (G=8, 35 KB LDS -> 4 blocks/CU, 16 waves/CU — the
// best-measured config) with round-1's proven direct-final-position tail.
__global__ __launch_bounds__(256) void p2_experts(
    const float* __restrict__ x,
    const float* __restrict__ wg, const float* __restrict__ wu,
    const int* __restrict__ count, const int* __restrict__ tok_list,
    float* __restrict__ out)
{
    __shared__ float4 sx[G * NF4];           // 32 KB
    __shared__ float  sred[G][NEXP];         // 2 KB  [token][row 0..63]
    __shared__ float  sscore[G][ROWS];       // 1 KB
    __shared__ int    s_entry[G];

    const int e = blockIdx.x, c0 = blockIdx.y;
    const int n = count[e];
    const int i0 = c0 * G;
    if (i0 >= n) return;
    const int T = (n - i0 < G) ? (n - i0) : G;

    const int t = threadIdx.x;
    const int g = t >> 4, j = t & 15;

    if (t < G)
        s_entry[t] = tok_list[e * 1024 + i0 + ((t < T) ? t : 0)];  // clamp -> dup work
    __syncthreads();

    {   // stage G token rows, coalesced
        #pragma unroll
        for (int i = 0; i < G; ++i)
            sx[i * NF4 + t] =
                ((const float4*)(x + (size_t)(s_entry[i] >> 6) * HIDDEN))[t];
    }
    __syncthreads();

    const float4* wp[4];
    #pragma unroll
    for (int m = 0; m < 4; ++m) {
        const int R = g + 16 * m;            // 0..31 gate rows, 32..63 up rows
        wp[m] = (const float4*)((R < ROWS)
            ? wg + ((size_t)e * ROWS + R) * HIDDEN
            : wu + ((size_t)e * ROWS + (R - ROWS)) * HIDDEN);
    }

    float acc[4][G];
    #pragma unroll
    for (int m = 0; m < 4; ++m)
        #pragma unroll
        for (int tk = 0; tk < G; ++tk) acc[m][tk] = 0.f;

    #pragma unroll 2
    for (int k = 0; k < 16; ++k) {
        const int c = j + 16 * k;
        float4 wf[4];
        #pragma unroll
        for (int m = 0; m < 4; ++m) wf[m] = wp[m][c];
        #pragma unroll
        for (int tk = 0; tk < G; ++tk) {
            float4 xb = sx[tk * NF4 + c];
            #pragma unroll
            for (int m = 0; m < 4; ++m) acc[m][tk] += dot4(wf[m], xb);
        }
    }

    #pragma unroll
    for (int m = 0; m < 4; ++m)
        #pragma unroll
        for (int tk = 0; tk < G; ++tk) {
            float v = acc[m][tk];
            v += __shfl_xor(v, 1); v += __shfl_xor(v, 2);
            v += __shfl_xor(v, 4); v += __shfl_xor(v, 8);
            acc[m][tk] = v;
        }
    if (j == 0)
        #pragma unroll
        for (int m = 0; m < 4; ++m)
            #pragma unroll
            for (int tk = 0; tk < G; ++tk)
                sred[tk][g + 16 * m] = acc[m][tk];
    __syncthreads();

    {   // silu-gate-abs: 256 threads cover 8 tok x 32 rows exactly
        const int tok = t >> 5, rr = t & 31;
        const float gg = sred[tok][rr], uu = sred[tok][rr + 32];
        sscore[tok][rr] = fabsf(uu * (gg / (1.f + expf(-gg))));
    }
    __syncthreads();

    if (t < T) {
        const int entry = s_entry[t];
        const int token = entry >> 6, slot = (entry >> 3) & 3, off = entry & 7;
        float inner[INNER];
        #pragma unroll
        for (int i = 0; i < INNER; ++i)
            inner[i] = 0.25f * (sscore[t][4*i] + sscore[t][4*i+1]
                              + sscore[t][4*i+2] + sscore[t][4*i+3]);
        const int kk = (slot == 0) ? 3 : ((slot == 3) ? 1 : 2);
        int picked[3];
        for (int k = 0; k < kk; ++k) {
            float best = -INFINITY; int bi = 0;
            #pragma unroll
            for (int i = 0; i < INNER; ++i)
                if (inner[i] > best) { best = inner[i]; bi = i; }  // ties -> lowest idx
            inner[bi] = -INFINITY;
            picked[k] = bi;
        }
        for (int a = 1; a < kk; ++a) {       // sort inner ids descending (kk<=3)
            int vv = picked[a]; int b = a - 1;
            while (b >= 0 && picked[b] < vv) { picked[b+1] = picked[b]; --b; }
            picked[b+1] = vv;
        }
        // experts descend across pairs (off from p1), inner ids descend within
        // the pair -> exactly reference's top-8 order
        float* oid = out + (size_t)token * TOTAL + off;
        for (int k = 0; k < kk; ++k) oid[k] = (float)(e * INNER + picked[k]);
    }
}

extern "C" void kernel_launch(void* const* d_in, const int* in_sizes, int n_in,
                              void* d_out, int out_size, void* d_ws, size_t ws_size,
                              hipStream_t stream) {
    const float* x  = (const float*)d_in[0];
    const float* rw = (const float*)d_in[1];
    const float* wg = (const float*)d_in[2];
    const float* wu = (const float*)d_in[3];
    float* out = (float*)d_out;
    const int bs = in_sizes[0] / HIDDEN;   // 1024

    // workspace: count[64] | tok_list[64*1024]
    int* count    = (int*)d_ws;
    int* tok_list = count + 64;

    hipMemsetAsync(count, 0, 64 * sizeof(int), stream);
    hipLaunchKernelGGL(p1_router, dim3(bs / TB), dim3(256), 0, stream,
                       x, rw, count, tok_list, out, bs);
    hipLaunchKernelGGL(p2_experts, dim3(NEXP, MAXCH), dim3(256), 0, stream,
                       x, wg, wu, count, tok_list, out);
}